// Round 1
// baseline (336.462 us; speedup 1.0000x reference)
//
#include <hip/hip_runtime.h>
#include <hip/hip_bf16.h>
#include <stdint.h>

#define Bb   512
#define Tt   2048
#define Dd   32
#define Ee   64
#define Kk   8
#define OUTn 1024

typedef __attribute__((ext_vector_type(4))) float f32x4;
typedef __attribute__((ext_vector_type(8))) short short8;
typedef __attribute__((ext_vector_type(4))) unsigned int uint4v;

static __device__ __forceinline__ uint32_t f2bf(float f) {
  // round-to-nearest-even f32 -> bf16 bits
  uint32_t u = __float_as_uint(f);
  return (u + 0x7FFFu + ((u >> 16) & 1u)) >> 16;
}
static __device__ __forceinline__ uint32_t umax32(uint32_t a, uint32_t b){ return a > b ? a : b; }
static __device__ __forceinline__ uint32_t umin32(uint32_t a, uint32_t b){ return a < b ? a : b; }

// ---------------------------------------------------------------------------
// Kernel A: per-batch gating. bf16-MFMA logits -> +gumbel selection scores ->
// per-(b,e) top-16 candidates -> f64 exact rescore -> top-8 -> gather x rows
// (bf16) into ws.  No log-softmax needed: constant shifts per (b,e) don't
// change top-k ordering.
// ---------------------------------------------------------------------------
__global__ __launch_bounds__(512) void kA_select(
    const float* __restrict__ x,        // [B,T,D]
    const float* __restrict__ gate_w,   // [E,D]
    const float* __restrict__ gumbel,   // [B,E,T]
    uint16_t* __restrict__ inp)         // ws: [B,E,K*D] bf16 bits
{
  const int b    = blockIdx.x;
  const int tid  = threadIdx.x;
  const int wave = tid >> 6;
  const int lane = tid & 63;
  const int l15  = lane & 15;
  const int l4   = lane >> 4;

  __shared__ __attribute__((aligned(16))) float r_tile[Ee * 256]; // [e][t] 64 KB

  // Persistent A-frags: gate_w rows as bf16 (A = gw: 16e x 32d per chunk)
  // A-frag: row = lane&15, k = (lane>>4)*8 + j  (8 contiguous elements)
  short8 gfrag[4];
  #pragma unroll
  for (int c = 0; c < 4; ++c) {
    const float* gp = gate_w + (size_t)(c * 16 + l15) * Dd + l4 * 8;
    f32x4 g0 = *(const f32x4*)(gp);
    f32x4 g1 = *(const f32x4*)(gp + 4);
    short8 v;
    v[0] = (short)f2bf(g0[0]); v[1] = (short)f2bf(g0[1]);
    v[2] = (short)f2bf(g0[2]); v[3] = (short)f2bf(g0[3]);
    v[4] = (short)f2bf(g1[0]); v[5] = (short)f2bf(g1[1]);
    v[6] = (short)f2bf(g1[2]); v[7] = (short)f2bf(g1[3]);
    gfrag[c] = v;
  }

  // per-lane top-6 packed keys for each of this wave's 8 experts
  // key = (monotone_f32 & ~0x7FF) | (2047 - t)   (ties -> lower t wins)
  uint32_t s[6][8];
  #pragma unroll
  for (int sl = 0; sl < 6; ++sl)
    #pragma unroll
    for (int el = 0; el < 8; ++el) s[sl][el] = 0u;

  for (int tile = 0; tile < 8; ++tile) {
    // ---- MFMA logits for this 256-token tile: D[e][t] = gw . x^T ----
    #pragma unroll
    for (int tf = 0; tf < 2; ++tf) {
      const int tloc = wave * 32 + tf * 16;           // t within tile, frag base
      // B-frag: col = lane&15 -> t, k = (lane>>4)*8 + j -> d  (8 contiguous f32 of x row)
      const float* xp = x + ((size_t)b * Tt + tile * 256 + tloc + l15) * Dd + l4 * 8;
      f32x4 x0 = *(const f32x4*)(xp);
      f32x4 x1 = *(const f32x4*)(xp + 4);
      short8 bfr;
      bfr[0] = (short)f2bf(x0[0]); bfr[1] = (short)f2bf(x0[1]);
      bfr[2] = (short)f2bf(x0[2]); bfr[3] = (short)f2bf(x0[3]);
      bfr[4] = (short)f2bf(x1[0]); bfr[5] = (short)f2bf(x1[1]);
      bfr[6] = (short)f2bf(x1[2]); bfr[7] = (short)f2bf(x1[3]);
      #pragma unroll
      for (int c = 0; c < 4; ++c) {
        f32x4 acc = {0.f, 0.f, 0.f, 0.f};
        acc = __builtin_amdgcn_mfma_f32_16x16x32_bf16(gfrag[c], bfr, acc, 0, 0, 0);
        // D: col = lane&15 -> t, row = (lane>>4)*4 + reg -> e(within chunk)
        #pragma unroll
        for (int reg = 0; reg < 4; ++reg)
          r_tile[(c * 16 + l4 * 4 + reg) * 256 + tloc + l15] = acc[reg];
      }
    }
    __syncthreads();

    // ---- selection sweep: wave owns experts wave*8 .. wave*8+7 ----
    #pragma unroll
    for (int el = 0; el < 8; ++el) {
      const int e = wave * 8 + el;
      f32x4 lv = *(const f32x4*)&r_tile[e * 256 + lane * 4];
      f32x4 gv = *(const f32x4*)(gumbel + ((size_t)b * Ee + e) * Tt + tile * 256 + lane * 4);
      #pragma unroll
      for (int j = 0; j < 4; ++j) {
        float rr = lv[j] + gv[j];
        uint32_t u = __float_as_uint(rr);
        u = (u & 0x80000000u) ? ~u : (u | 0x80000000u);  // monotone total order
        uint32_t key = (u & 0xFFFFF800u) | (2047u - (uint32_t)(tile * 256 + lane * 4 + j));
        // branchless sorted insert (s[0] largest .. s[5] smallest)
        uint32_t c = umax32(s[5][el], key);
        uint32_t d;
        d = s[4][el]; s[5][el] = umin32(d, c); c = umax32(d, c);
        d = s[3][el]; s[4][el] = umin32(d, c); c = umax32(d, c);
        d = s[2][el]; s[3][el] = umin32(d, c); c = umax32(d, c);
        d = s[1][el]; s[2][el] = umin32(d, c); c = umax32(d, c);
        d = s[0][el]; s[1][el] = umin32(d, c); s[0][el] = umax32(d, c);
      }
    }
    __syncthreads();
  }

  // ---- per expert: merge to top-16, f64 rescore, sort top-8, gather ----
  #pragma unroll
  for (int el = 0; el < 8; ++el) {
    const int e = wave * 8 + el;
    uint32_t myT = 0;
    #pragma unroll
    for (int rnd = 0; rnd < 16; ++rnd) {
      uint32_t cur = s[0][el];
      uint32_t mx = cur;
      #pragma unroll
      for (int off = 1; off < 64; off <<= 1)
        mx = umax32(mx, (uint32_t)__shfl_xor((int)mx, off));
      uint32_t tw = 2047u - (mx & 2047u);
      if (lane == rnd) myT = tw;
      if (cur == mx) {  // unique winner (t embedded in key)
        s[0][el] = s[1][el]; s[1][el] = s[2][el]; s[2][el] = s[3][el];
        s[3][el] = s[4][el]; s[4][el] = s[5][el]; s[5][el] = 0u;
      }
    }

    // f64 rescore of 16 candidates (lanes 0..15)
    const bool alive = lane < 16;
    double sc = -1e300;
    if (alive) {
      const float* xr = x + ((size_t)b * Tt + myT) * Dd;
      const float* gr = gate_w + (size_t)e * Dd;
      double a = 0.0;
      #pragma unroll
      for (int d = 0; d < Dd; ++d) a += (double)xr[d] * (double)gr[d];
      sc = a + (double)gumbel[((size_t)b * Ee + e) * Tt + myT];
    }
    uint32_t ti = alive ? myT : 0xFFFFu;
    double v = sc;
    uint32_t ord[8];
    #pragma unroll
    for (int k = 0; k < 8; ++k) {
      double bv = v; uint32_t bt = ti;
      #pragma unroll
      for (int off = 1; off < 64; off <<= 1) {
        double   ov = __shfl_xor(bv, off);
        uint32_t ot = (uint32_t)__shfl_xor((int)bt, off);
        if (ov > bv || (ov == bv && ot < bt)) { bv = ov; bt = ot; }
      }
      ord[k] = bt;           // uniform across lanes
      if (ti == bt) v = -1e300;
    }

    // gather: wave writes inp[b][e][0..255] (8 tokens x 32 feats, bf16)
    const int kk = lane >> 3, sub = lane & 7;
    uint32_t tk = ord[0];
    #pragma unroll
    for (int q = 1; q < 8; ++q) tk = (kk == q) ? ord[q] : tk;
    const float* xs = x + ((size_t)b * Tt + tk) * Dd + sub * 4;
    f32x4 xv = *(const f32x4*)xs;
    uint32_t p0 = f2bf(xv[0]) | (f2bf(xv[1]) << 16);
    uint32_t p1 = f2bf(xv[2]) | (f2bf(xv[3]) << 16);
    uint32_t* dst = (uint32_t*)inp + ((((size_t)b * Ee + e) * 256) + kk * 32 + sub * 4) / 2;
    dst[0] = p0; dst[1] = p1;
  }
}

// ---------------------------------------------------------------------------
// Kernel B: grouped per-expert GEMM  out[b,e,:] = inp[b,e,:] . W[e]^T + bias
// 128x128 tile, K=256 in 4 steps, bf16 MFMA, W converted f32->bf16 in staging.
// ---------------------------------------------------------------------------
__global__ __launch_bounds__(256) void kB_gemm(
    const uint16_t* __restrict__ inp,      // [B,E,256] bf16 bits
    const float* __restrict__ expert_w,    // [E,OUT,256]
    const float* __restrict__ expert_b,    // [E,OUT]
    float* __restrict__ out)               // [B,E,OUT]
{
  const int id = blockIdx.x;                 // ((e*4 + m)*8) + n
  const int e  = id >> 5;
  const int mb = (id >> 3) & 3;
  const int nb = id & 7;
  const int b0 = mb * 128;
  const int o0 = nb * 128;
  const int tid  = threadIdx.x;
  const int wave = tid >> 6;
  const int lane = tid & 63;
  const int l15 = lane & 15, l4 = lane >> 4;
  const int wm = (wave & 1) * 64;
  const int wn = (wave >> 1) * 64;

  __shared__ __attribute__((aligned(16))) uint32_t Al[128 * 32]; // [m][64 bf16] swizzled
  __shared__ __attribute__((aligned(16))) uint32_t Wl[128 * 32]; // [o][64 bf16] swizzled

  f32x4 acc[4][4];
  #pragma unroll
  for (int i = 0; i < 4; ++i)
    #pragma unroll
    for (int j = 0; j < 4; ++j) acc[i][j] = (f32x4){0.f, 0.f, 0.f, 0.f};

  for (int ks = 0; ks < 4; ++ks) {
    // stage A (already bf16): 128 rows x 64k
    #pragma unroll
    for (int i = 0; i < 4; ++i) {
      int gi = tid + i * 256;
      int m = gi >> 3, q = gi & 7;
      const uint4v* src = (const uint4v*)(inp + ((size_t)(b0 + m) * Ee + e) * 256 + ks * 64 + q * 8);
      *(uint4v*)&Al[m * 32 + ((q ^ (m & 7)) * 4)] = *src;
    }
    // stage W with f32 -> bf16 conversion
    #pragma unroll
    for (int i = 0; i < 4; ++i) {
      int gi = tid + i * 256;
      int o = gi >> 3, q = gi & 7;
      const float* src = expert_w + ((size_t)e * OUTn + o0 + o) * 256 + ks * 64 + q * 8;
      f32x4 w0 = *(const f32x4*)src;
      f32x4 w1 = *(const f32x4*)(src + 4);
      uint4v v;
      v[0] = f2bf(w0[0]) | (f2bf(w0[1]) << 16);
      v[1] = f2bf(w0[2]) | (f2bf(w0[3]) << 16);
      v[2] = f2bf(w1[0]) | (f2bf(w1[1]) << 16);
      v[3] = f2bf(w1[2]) | (f2bf(w1[3]) << 16);
      *(uint4v*)&Wl[o * 32 + ((q ^ (o & 7)) * 4)] = v;
    }
    __syncthreads();

    short8 af[4][2], bf[4][2];
    #pragma unroll
    for (int mf = 0; mf < 4; ++mf)
      #pragma unroll
      for (int kb = 0; kb < 2; ++kb) {
        int row = wm + mf * 16 + l15;
        int g = kb * 4 + l4;
        af[mf][kb] = *(const short8*)&Al[row * 32 + ((g ^ (row & 7)) * 4)];
      }
    #pragma unroll
    for (int nf = 0; nf < 4; ++nf)
      #pragma unroll
      for (int kb = 0; kb < 2; ++kb) {
        int row = wn + nf * 16 + l15;
        int g = kb * 4 + l4;
        bf[nf][kb] = *(const short8*)&Wl[row * 32 + ((g ^ (row & 7)) * 4)];
      }
    #pragma unroll
    for (int mf = 0; mf < 4; ++mf)
      #pragma unroll
      for (int nf = 0; nf < 4; ++nf)
        #pragma unroll
        for (int kb = 0; kb < 2; ++kb)
          acc[mf][nf] = __builtin_amdgcn_mfma_f32_16x16x32_bf16(af[mf][kb], bf[nf][kb], acc[mf][nf], 0, 0, 0);
    __syncthreads();
  }

  // epilogue: D col = lane&15 -> o, row = (lane>>4)*4+reg -> b-row
  #pragma unroll
  for (int nf = 0; nf < 4; ++nf) {
    const int ocol = o0 + wn + nf * 16 + l15;
    const float bias = expert_b[(size_t)e * OUTn + ocol];
    #pragma unroll
    for (int mf = 0; mf < 4; ++mf) {
      #pragma unroll
      for (int reg = 0; reg < 4; ++reg) {
        const int mrow = b0 + wm + mf * 16 + l4 * 4 + reg;
        out[((size_t)mrow * Ee + e) * OUTn + ocol] = acc[mf][nf][reg] + bias;
      }
    }
  }
}

extern "C" void kernel_launch(void* const* d_in, const int* in_sizes, int n_in,
                              void* d_out, int out_size, void* d_ws, size_t ws_size,
                              hipStream_t stream) {
  const float* x        = (const float*)d_in[0];
  const float* gate_w   = (const float*)d_in[1];
  // d_in[2] = gate_b: constant per expert -> cannot change per-(b,e) top-k
  // ordering over tokens (and is zeros); values are never used downstream.
  const float* expert_w = (const float*)d_in[3];
  const float* expert_b = (const float*)d_in[4];
  const float* gumbel   = (const float*)d_in[5];

  uint16_t* inp = (uint16_t*)d_ws;   // 512*64*256*2 = 16.8 MB

  kA_select<<<Bb, 512, 0, stream>>>(x, gate_w, gumbel, inp);
  kB_gemm<<<2048, 256, 0, stream>>>(inp, expert_w, expert_b, (float*)d_out);
}

// Round 2
// 262.953 us; speedup vs baseline: 1.2796x; 1.2796x over previous
//
#include <hip/hip_runtime.h>
#include <hip/hip_bf16.h>
#include <stdint.h>

#define Bb   512
#define Tt   2048
#define Dd   32
#define Ee   64
#define Kk   8
#define OUTn 1024

typedef __attribute__((ext_vector_type(4))) float f32x4;
typedef __attribute__((ext_vector_type(2))) float f32x2;
typedef __attribute__((ext_vector_type(8))) short short8;
typedef __attribute__((ext_vector_type(4))) unsigned int uint4v;

static __device__ __forceinline__ uint32_t f2bf(float f) {
  // round-to-nearest-even f32 -> bf16 bits
  uint32_t u = __float_as_uint(f);
  return (u + 0x7FFFu + ((u >> 16) & 1u)) >> 16;
}
static __device__ __forceinline__ uint32_t umax32(uint32_t a, uint32_t b){ return a > b ? a : b; }
static __device__ __forceinline__ uint32_t umin32(uint32_t a, uint32_t b){ return a < b ? a : b; }

#define RT_STRIDE 130   // floats; stride%32==2 -> MFMA D-stores <=2-way, f32x2 sweep reads uniform

// ---------------------------------------------------------------------------
// Kernel A: per-batch gating. bf16-MFMA logits -> +gumbel selection scores ->
// per-(b,e) top-16 candidates -> f64 exact rescore -> top-8 -> gather x rows
// (bf16) into ws.  log-softmax skipped: per-(b,e)-constant shifts don't
// change top-k ordering over tokens.
// Structure: 16 subtiles x 128 tokens; LDS 33 KB so 2 blocks/CU co-resident;
// gumbel prefetched into regs before the MFMA phase (latency hidden).
// ---------------------------------------------------------------------------
__global__ __launch_bounds__(512) void kA_select(
    const float* __restrict__ x,        // [B,T,D]
    const float* __restrict__ gate_w,   // [E,D]
    const float* __restrict__ gumbel,   // [B,E,T]
    uint16_t* __restrict__ inp)         // ws: [B,E,K*D] bf16 bits
{
  const int b    = blockIdx.x;
  const int tid  = threadIdx.x;
  const int wave = tid >> 6;
  const int lane = tid & 63;
  const int l15  = lane & 15;
  const int l4   = lane >> 4;

  __shared__ __attribute__((aligned(16))) float r_tile[Ee * RT_STRIDE]; // 33.3 KB

  // Persistent A-frags: gate_w rows as bf16 (A = gw: 16e x 32d per chunk)
  short8 gfrag[4];
  #pragma unroll
  for (int c = 0; c < 4; ++c) {
    const float* gp = gate_w + (size_t)(c * 16 + l15) * Dd + l4 * 8;
    f32x4 g0 = *(const f32x4*)(gp);
    f32x4 g1 = *(const f32x4*)(gp + 4);
    short8 v;
    v[0] = (short)f2bf(g0[0]); v[1] = (short)f2bf(g0[1]);
    v[2] = (short)f2bf(g0[2]); v[3] = (short)f2bf(g0[3]);
    v[4] = (short)f2bf(g1[0]); v[5] = (short)f2bf(g1[1]);
    v[6] = (short)f2bf(g1[2]); v[7] = (short)f2bf(g1[3]);
    gfrag[c] = v;
  }

  // per-lane top-6 packed keys for each of this wave's 8 experts
  // key = (monotone_f32 & ~0x7FF) | (2047 - t)   (ties -> lower t wins)
  uint32_t s[6][8];
  #pragma unroll
  for (int sl = 0; sl < 6; ++sl)
    #pragma unroll
    for (int el = 0; el < 8; ++el) s[sl][el] = 0u;

  for (int st = 0; st < 16; ++st) {
    const int t0 = st * 128;

    // ---- prefetch gumbel for this subtile (consumed after the barrier) ----
    f32x2 gvv[8];
    #pragma unroll
    for (int el = 0; el < 8; ++el) {
      const int e = wave * 8 + el;
      gvv[el] = *(const f32x2*)(gumbel + ((size_t)b * Ee + e) * Tt + t0 + lane * 2);
    }

    // ---- MFMA logits: D[e][t] = gw . x^T, this wave's 16-token frag ----
    {
      const int tloc = wave * 16;                       // t within subtile
      const float* xp = x + ((size_t)b * Tt + t0 + tloc + l15) * Dd + l4 * 8;
      f32x4 x0 = *(const f32x4*)(xp);
      f32x4 x1 = *(const f32x4*)(xp + 4);
      short8 bfr;
      bfr[0] = (short)f2bf(x0[0]); bfr[1] = (short)f2bf(x0[1]);
      bfr[2] = (short)f2bf(x0[2]); bfr[3] = (short)f2bf(x0[3]);
      bfr[4] = (short)f2bf(x1[0]); bfr[5] = (short)f2bf(x1[1]);
      bfr[6] = (short)f2bf(x1[2]); bfr[7] = (short)f2bf(x1[3]);
      #pragma unroll
      for (int c = 0; c < 4; ++c) {
        f32x4 acc = {0.f, 0.f, 0.f, 0.f};
        acc = __builtin_amdgcn_mfma_f32_16x16x32_bf16(gfrag[c], bfr, acc, 0, 0, 0);
        #pragma unroll
        for (int reg = 0; reg < 4; ++reg)
          r_tile[(c * 16 + l4 * 4 + reg) * RT_STRIDE + tloc + l15] = acc[reg];
      }
    }
    __syncthreads();

    // ---- selection sweep: wave owns experts wave*8 .. wave*8+7 ----
    #pragma unroll
    for (int el = 0; el < 8; ++el) {
      const int e = wave * 8 + el;
      f32x2 lv = *(const f32x2*)&r_tile[e * RT_STRIDE + lane * 2];
      #pragma unroll
      for (int j = 0; j < 2; ++j) {
        float rr = lv[j] + gvv[el][j];
        uint32_t u = __float_as_uint(rr);
        u = (u & 0x80000000u) ? ~u : (u | 0x80000000u);  // monotone total order
        uint32_t key = (u & 0xFFFFF800u) | (2047u - (uint32_t)(t0 + lane * 2 + j));
        uint32_t c = umax32(s[5][el], key);
        uint32_t d;
        d = s[4][el]; s[5][el] = umin32(d, c); c = umax32(d, c);
        d = s[3][el]; s[4][el] = umin32(d, c); c = umax32(d, c);
        d = s[2][el]; s[3][el] = umin32(d, c); c = umax32(d, c);
        d = s[1][el]; s[2][el] = umin32(d, c); c = umax32(d, c);
        d = s[0][el]; s[1][el] = umin32(d, c); s[0][el] = umax32(d, c);
      }
    }
    __syncthreads();
  }

  // ---- per expert: merge to top-16, f64 rescore, sort top-8, gather ----
  #pragma unroll
  for (int el = 0; el < 8; ++el) {
    const int e = wave * 8 + el;
    uint32_t myT = 0;
    #pragma unroll
    for (int rnd = 0; rnd < 16; ++rnd) {
      uint32_t cur = s[0][el];
      uint32_t mx = cur;
      #pragma unroll
      for (int off = 1; off < 64; off <<= 1)
        mx = umax32(mx, (uint32_t)__shfl_xor((int)mx, off));
      uint32_t tw = 2047u - (mx & 2047u);
      if (lane == rnd) myT = tw;
      if (cur == mx) {  // unique winner (t embedded in key)
        s[0][el] = s[1][el]; s[1][el] = s[2][el]; s[2][el] = s[3][el];
        s[3][el] = s[4][el]; s[4][el] = s[5][el]; s[5][el] = 0u;
      }
    }

    // f64 rescore of 16 candidates (lanes 0..15)
    const bool alive = lane < 16;
    double sc = -1e300;
    if (alive) {
      const float* xr = x + ((size_t)b * Tt + myT) * Dd;
      const float* gr = gate_w + (size_t)e * Dd;
      double a = 0.0;
      #pragma unroll
      for (int d = 0; d < Dd; ++d) a += (double)xr[d] * (double)gr[d];
      sc = a + (double)gumbel[((size_t)b * Ee + e) * Tt + myT];
    }
    uint32_t ti = alive ? myT : 0xFFFFu;
    double v = sc;
    uint32_t ord[8];
    #pragma unroll
    for (int k = 0; k < 8; ++k) {
      double bv = v; uint32_t bt = ti;
      #pragma unroll
      for (int off = 1; off < 64; off <<= 1) {
        double   ov = __shfl_xor(bv, off);
        uint32_t ot = (uint32_t)__shfl_xor((int)bt, off);
        if (ov > bv || (ov == bv && ot < bt)) { bv = ov; bt = ot; }
      }
      ord[k] = bt;           // uniform across lanes
      if (ti == bt) v = -1e300;
    }

    // gather: wave writes inp[b][e][0..255] (8 tokens x 32 feats, bf16)
    const int kk = lane >> 3, sub = lane & 7;
    uint32_t tk = ord[0];
    #pragma unroll
    for (int q = 1; q < 8; ++q) tk = (kk == q) ? ord[q] : tk;
    const float* xs = x + ((size_t)b * Tt + tk) * Dd + sub * 4;
    f32x4 xv = *(const f32x4*)xs;
    uint32_t p0 = f2bf(xv[0]) | (f2bf(xv[1]) << 16);
    uint32_t p1 = f2bf(xv[2]) | (f2bf(xv[3]) << 16);
    uint32_t* dst = (uint32_t*)inp + ((((size_t)b * Ee + e) * 256) + kk * 32 + sub * 4) / 2;
    dst[0] = p0; dst[1] = p1;
  }
}

// ---------------------------------------------------------------------------
// Kernel B: grouped per-expert GEMM  out[b,e,:] = inp[b,e,:] . W[e]^T + bias
// 128x128 tile, K=256 in 4 steps, bf16 MFMA, W converted f32->bf16 in staging.
// XCD-aware decode: expert e's 32 blocks all land on XCD e/8 -> W slices hit L2.
// ---------------------------------------------------------------------------
__global__ __launch_bounds__(256) void kB_gemm(
    const uint16_t* __restrict__ inp,      // [B,E,256] bf16 bits
    const float* __restrict__ expert_w,    // [E,OUT,256]
    const float* __restrict__ expert_b,    // [E,OUT]
    float* __restrict__ out)               // [B,E,OUT]
{
  const int bid = blockIdx.x;                // 2048 blocks
  const int xcd = bid & 7;
  const int idx = bid >> 3;                  // 0..255
  const int e   = xcd * 8 + (idx >> 5);      // 8 experts per XCD
  const int rem = idx & 31;
  const int mb  = rem >> 3;
  const int nb  = rem & 7;
  const int b0 = mb * 128;
  const int o0 = nb * 128;
  const int tid  = threadIdx.x;
  const int wave = tid >> 6;
  const int lane = tid & 63;
  const int l15 = lane & 15, l4 = lane >> 4;
  const int wm = (wave & 1) * 64;
  const int wn = (wave >> 1) * 64;

  __shared__ __attribute__((aligned(16))) uint32_t Al[128 * 32]; // [m][64 bf16] swizzled
  __shared__ __attribute__((aligned(16))) uint32_t Wl[128 * 32]; // [o][64 bf16] swizzled

  f32x4 acc[4][4];
  #pragma unroll
  for (int i = 0; i < 4; ++i)
    #pragma unroll
    for (int j = 0; j < 4; ++j) acc[i][j] = (f32x4){0.f, 0.f, 0.f, 0.f};

  for (int ks = 0; ks < 4; ++ks) {
    // stage A (already bf16): 128 rows x 64k
    #pragma unroll
    for (int i = 0; i < 4; ++i) {
      int gi = tid + i * 256;
      int m = gi >> 3, q = gi & 7;
      const uint4v* src = (const uint4v*)(inp + ((size_t)(b0 + m) * Ee + e) * 256 + ks * 64 + q * 8);
      *(uint4v*)&Al[m * 32 + ((q ^ (m & 7)) * 4)] = *src;
    }
    // stage W with f32 -> bf16 conversion
    #pragma unroll
    for (int i = 0; i < 4; ++i) {
      int gi = tid + i * 256;
      int o = gi >> 3, q = gi & 7;
      const float* src = expert_w + ((size_t)e * OUTn + o0 + o) * 256 + ks * 64 + q * 8;
      f32x4 w0 = *(const f32x4*)src;
      f32x4 w1 = *(const f32x4*)(src + 4);
      uint4v v;
      v[0] = f2bf(w0[0]) | (f2bf(w0[1]) << 16);
      v[1] = f2bf(w0[2]) | (f2bf(w0[3]) << 16);
      v[2] = f2bf(w1[0]) | (f2bf(w1[1]) << 16);
      v[3] = f2bf(w1[2]) | (f2bf(w1[3]) << 16);
      *(uint4v*)&Wl[o * 32 + ((q ^ (o & 7)) * 4)] = v;
    }
    __syncthreads();

    short8 af[4][2], bf[4][2];
    #pragma unroll
    for (int mf = 0; mf < 4; ++mf)
      #pragma unroll
      for (int kb = 0; kb < 2; ++kb) {
        int row = wm + mf * 16 + l15;
        int g = kb * 4 + l4;
        af[mf][kb] = *(const short8*)&Al[row * 32 + ((g ^ (row & 7)) * 4)];
      }
    #pragma unroll
    for (int nf = 0; nf < 4; ++nf)
      #pragma unroll
      for (int kb = 0; kb < 2; ++kb) {
        int row = wn + nf * 16 + l15;
        int g = kb * 4 + l4;
        bf[nf][kb] = *(const short8*)&Wl[row * 32 + ((g ^ (row & 7)) * 4)];
      }
    #pragma unroll
    for (int mf = 0; mf < 4; ++mf)
      #pragma unroll
      for (int nf = 0; nf < 4; ++nf)
        #pragma unroll
        for (int kb = 0; kb < 2; ++kb)
          acc[mf][nf] = __builtin_amdgcn_mfma_f32_16x16x32_bf16(af[mf][kb], bf[nf][kb], acc[mf][nf], 0, 0, 0);
    __syncthreads();
  }

  // epilogue: D col = lane&15 -> o, row = (lane>>4)*4+reg -> b-row
  #pragma unroll
  for (int nf = 0; nf < 4; ++nf) {
    const int ocol = o0 + wn + nf * 16 + l15;
    const float bias = expert_b[(size_t)e * OUTn + ocol];
    #pragma unroll
    for (int mf = 0; mf < 4; ++mf) {
      #pragma unroll
      for (int reg = 0; reg < 4; ++reg) {
        const int mrow = b0 + wm + mf * 16 + l4 * 4 + reg;
        out[((size_t)mrow * Ee + e) * OUTn + ocol] = acc[mf][nf][reg] + bias;
      }
    }
  }
}

extern "C" void kernel_launch(void* const* d_in, const int* in_sizes, int n_in,
                              void* d_out, int out_size, void* d_ws, size_t ws_size,
                              hipStream_t stream) {
  const float* x        = (const float*)d_in[0];
  const float* gate_w   = (const float*)d_in[1];
  // d_in[2] = gate_b: constant per expert -> cannot change per-(b,e) top-k
  // ordering over tokens (and is zeros); values are never used downstream.
  const float* expert_w = (const float*)d_in[3];
  const float* expert_b = (const float*)d_in[4];
  const float* gumbel   = (const float*)d_in[5];

  uint16_t* inp = (uint16_t*)d_ws;   // 512*64*256*2 = 16.8 MB

  kA_select<<<Bb, 512, 0, stream>>>(x, gate_w, gumbel, inp);
  kB_gemm<<<2048, 256, 0, stream>>>(inp, expert_w, expert_b, (float*)d_out);
}

// Round 3
// 246.295 us; speedup vs baseline: 1.3661x; 1.0676x over previous
//
#include <hip/hip_runtime.h>
#include <hip/hip_bf16.h>
#include <stdint.h>

#define Bb   512
#define Tt   2048
#define Dd   32
#define Ee   64
#define Kk   8
#define OUTn 1024

typedef __attribute__((ext_vector_type(4))) float f32x4;
typedef __attribute__((ext_vector_type(8))) short short8;
typedef __attribute__((ext_vector_type(4))) unsigned int uint4v;

static __device__ __forceinline__ uint32_t f2bf(float f) {
  // round-to-nearest-even f32 -> bf16 bits (bit-identical to R1/R2 passing runs)
  uint32_t u = __float_as_uint(f);
  return (u + 0x7FFFu + ((u >> 16) & 1u)) >> 16;
}
static __device__ __forceinline__ uint32_t umax32(uint32_t a, uint32_t b){ return a > b ? a : b; }
static __device__ __forceinline__ uint32_t umin32(uint32_t a, uint32_t b){ return a < b ? a : b; }

// ---------------------------------------------------------------------------
// Kernel A (barrier-free main loop): wave = (chunk c of 16 experts, token
// half h of 1024). Per 16-token step: one mfma(gw_chunk, x_frag) yields
// scores for experts c*16+l4*4+reg at token t0+l15 -> gumbel is 4 direct
// dword loads in exactly that layout (no LDS bounce, no __syncthreads).
// Per-lane branchless sorted top-8 (each expert spread over 16 lanes);
// per-(expert,half) top-16 extracted via 4-step shfl reduce into LDS;
// single barrier; f64 rescore of 32 candidates -> exact top-8 -> gather.
// log-softmax skipped: per-(b,e)-constant shifts don't change ordering.
// ---------------------------------------------------------------------------
__global__ __launch_bounds__(512, 4) void kA_select(
    const float* __restrict__ x,        // [B,T,D]
    const float* __restrict__ gate_w,   // [E,D]
    const float* __restrict__ gumbel,   // [B,E,T]
    uint16_t* __restrict__ inp)         // ws: [B,E,K*D] bf16 bits
{
  const int b    = blockIdx.x;
  const int tid  = threadIdx.x;
  const int wave = tid >> 6;
  const int lane = tid & 63;
  const int l15  = lane & 15;
  const int l4   = lane >> 4;
  const int c    = wave & 3;   // expert chunk: experts c*16 .. c*16+15
  const int h    = wave >> 2;  // token half: [h*1024, h*1024+1024)

  __shared__ uint32_t cand[Ee][32];   // 8 KB: per-expert 2x16 candidates

  // A-frag: gw[c*16 + l15][l4*8 + j]
  short8 gfrag;
  {
    const float* gp = gate_w + (size_t)(c * 16 + l15) * Dd + l4 * 8;
    f32x4 g0 = *(const f32x4*)(gp);
    f32x4 g1 = *(const f32x4*)(gp + 4);
    gfrag[0] = (short)f2bf(g0[0]); gfrag[1] = (short)f2bf(g0[1]);
    gfrag[2] = (short)f2bf(g0[2]); gfrag[3] = (short)f2bf(g0[3]);
    gfrag[4] = (short)f2bf(g1[0]); gfrag[5] = (short)f2bf(g1[1]);
    gfrag[6] = (short)f2bf(g1[2]); gfrag[7] = (short)f2bf(g1[3]);
  }

  // per-lane sorted top-8 keys per slot (slot r -> expert c*16 + l4*4 + r)
  // key = (monotone_f32 & ~0x7FF) | (2047 - t)   (ties -> lower t wins)
  uint32_t s[4][8];
  #pragma unroll
  for (int r = 0; r < 4; ++r)
    #pragma unroll
    for (int j = 0; j < 8; ++j) s[r][j] = 0u;

  const float* gum_base = gumbel + ((size_t)b * Ee + c * 16 + l4 * 4) * Tt + h * 1024 + l15;
  const float* x_base   = x + ((size_t)b * Tt + h * 1024 + l15) * Dd + l4 * 8;
  const int    tbase    = h * 1024 + l15;

  auto load_set = [&](float (&G)[8], f32x4 (&XV)[4], int ii) {
    #pragma unroll
    for (int ss = 0; ss < 2; ++ss) {
      #pragma unroll
      for (int r = 0; r < 4; ++r)
        G[ss * 4 + r] = gum_base[(size_t)r * Tt + ii * 32 + ss * 16];
      #pragma unroll
      for (int hv = 0; hv < 2; ++hv)
        XV[ss * 2 + hv] = *(const f32x4*)(x_base + (size_t)(ii * 32 + ss * 16) * Dd + hv * 4);
    }
  };

  auto proc_set = [&](float (&G)[8], f32x4 (&XV)[4], int ii) {
    #pragma unroll
    for (int ss = 0; ss < 2; ++ss) {
      f32x4 lo = XV[ss * 2], hi = XV[ss * 2 + 1];
      short8 bfr;
      bfr[0] = (short)f2bf(lo[0]); bfr[1] = (short)f2bf(lo[1]);
      bfr[2] = (short)f2bf(lo[2]); bfr[3] = (short)f2bf(lo[3]);
      bfr[4] = (short)f2bf(hi[0]); bfr[5] = (short)f2bf(hi[1]);
      bfr[6] = (short)f2bf(hi[2]); bfr[7] = (short)f2bf(hi[3]);
      f32x4 acc = {0.f, 0.f, 0.f, 0.f};
      acc = __builtin_amdgcn_mfma_f32_16x16x32_bf16(gfrag, bfr, acc, 0, 0, 0);
      const uint32_t tl = 2047u - (uint32_t)(tbase + ii * 32 + ss * 16);
      #pragma unroll
      for (int r = 0; r < 4; ++r) {
        float sc = acc[r] + G[ss * 4 + r];
        uint32_t u = __float_as_uint(sc);
        u = (u & 0x80000000u) ? ~u : (u | 0x80000000u);  // monotone total order
        uint32_t key = (u & 0xFFFFF800u) | tl;
        // branchless sorted insert, depth 8 (s[r][0] largest)
        uint32_t cc = umax32(s[r][7], key);
        uint32_t dd;
        dd = s[r][6]; s[r][7] = umin32(dd, cc); cc = umax32(dd, cc);
        dd = s[r][5]; s[r][6] = umin32(dd, cc); cc = umax32(dd, cc);
        dd = s[r][4]; s[r][5] = umin32(dd, cc); cc = umax32(dd, cc);
        dd = s[r][3]; s[r][4] = umin32(dd, cc); cc = umax32(dd, cc);
        dd = s[r][2]; s[r][3] = umin32(dd, cc); cc = umax32(dd, cc);
        dd = s[r][1]; s[r][2] = umin32(dd, cc); cc = umax32(dd, cc);
        dd = s[r][0]; s[r][1] = umin32(dd, cc); s[r][0] = umax32(dd, cc);
      }
    }
  };

  // main loop: 32 iterations x 32 tokens, depth-1 prefetch, NO barriers
  float gA[8]; f32x4 xA[4];
  float gB[8]; f32x4 xB[4];
  load_set(gA, xA, 0);
  for (int i = 0; i < 32; i += 2) {
    load_set(gB, xB, i + 1);
    proc_set(gA, xA, i);
    load_set(gA, xA, (i + 2 < 32) ? (i + 2) : 0);   // tail: harmless dummy reload
    proc_set(gB, xB, i + 1);
  }

  // ---- extract per-(expert,half) top-16 across the 16 lanes of each group ----
  #pragma unroll
  for (int r = 0; r < 4; ++r) {
    const int e_abs = c * 16 + l4 * 4 + r;
    #pragma unroll
    for (int rnd = 0; rnd < 16; ++rnd) {
      uint32_t cur = s[r][0];
      uint32_t mx = cur;
      mx = umax32(mx, (uint32_t)__shfl_xor((int)mx, 1));
      mx = umax32(mx, (uint32_t)__shfl_xor((int)mx, 2));
      mx = umax32(mx, (uint32_t)__shfl_xor((int)mx, 4));
      mx = umax32(mx, (uint32_t)__shfl_xor((int)mx, 8));
      if (l15 == rnd) cand[e_abs][h * 16 + rnd] = mx;
      const bool pop = (cur == mx);   // keys unique (t embedded) -> one lane
      s[r][0] = pop ? s[r][1] : s[r][0];
      s[r][1] = pop ? s[r][2] : s[r][1];
      s[r][2] = pop ? s[r][3] : s[r][2];
      s[r][3] = pop ? s[r][4] : s[r][3];
      s[r][4] = pop ? s[r][5] : s[r][4];
      s[r][5] = pop ? s[r][6] : s[r][5];
      s[r][6] = pop ? s[r][7] : s[r][6];
      s[r][7] = pop ? 0u      : s[r][7];
    }
  }
  __syncthreads();   // the only block-wide barrier

  // ---- per expert: f64 rescore of 32 candidates, top-8, gather ----
  #pragma unroll 1
  for (int el = 0; el < 8; ++el) {
    const int e = wave * 8 + el;
    const bool alive = lane < 32;
    uint32_t myT = 2047;
    double v = -1e300;
    if (alive) {
      uint32_t key = cand[e][lane];
      myT = 2047u - (key & 2047u);
      const float* xr = x + ((size_t)b * Tt + myT) * Dd;
      const float* gr = gate_w + (size_t)e * Dd;
      double a = 0.0;
      #pragma unroll
      for (int d = 0; d < Dd; ++d) a += (double)xr[d] * (double)gr[d];
      v = a + (double)gumbel[((size_t)b * Ee + e) * Tt + myT];
    }
    uint32_t ti = alive ? myT : 0xFFFFu;
    uint32_t ord[8];
    #pragma unroll
    for (int k = 0; k < 8; ++k) {
      double bv = v; uint32_t bt = ti;
      #pragma unroll
      for (int off = 1; off < 64; off <<= 1) {
        double   ov = __shfl_xor(bv, off);
        uint32_t ot = (uint32_t)__shfl_xor((int)bt, off);
        if (ov > bv || (ov == bv && ot < bt)) { bv = ov; bt = ot; }
      }
      ord[k] = bt;           // uniform across lanes
      if (ti == bt) v = -1e300;
    }

    // gather: wave writes inp[b][e][0..255] (8 tokens x 32 feats, bf16)
    const int kk = lane >> 3, sub = lane & 7;
    uint32_t tk = ord[0];
    #pragma unroll
    for (int q = 1; q < 8; ++q) tk = (kk == q) ? ord[q] : tk;
    const float* xs = x + ((size_t)b * Tt + tk) * Dd + sub * 4;
    f32x4 xv = *(const f32x4*)xs;
    uint32_t p0 = f2bf(xv[0]) | (f2bf(xv[1]) << 16);
    uint32_t p1 = f2bf(xv[2]) | (f2bf(xv[3]) << 16);
    uint32_t* dst = (uint32_t*)inp + ((((size_t)b * Ee + e) * 256) + kk * 32 + sub * 4) / 2;
    dst[0] = p0; dst[1] = p1;
  }
}

// ---------------------------------------------------------------------------
// Kernel B: grouped per-expert GEMM  out[b,e,:] = inp[b,e,:] . W[e]^T + bias
// 128x128 tile, K=256 in 4 steps, bf16 MFMA, W converted f32->bf16 in staging.
// XCD-aware decode: expert e's 32 blocks all land on XCD e/8 -> W slices hit L2.
// ---------------------------------------------------------------------------
__global__ __launch_bounds__(256) void kB_gemm(
    const uint16_t* __restrict__ inp,      // [B,E,256] bf16 bits
    const float* __restrict__ expert_w,    // [E,OUT,256]
    const float* __restrict__ expert_b,    // [E,OUT]
    float* __restrict__ out)               // [B,E,OUT]
{
  const int bid = blockIdx.x;                // 2048 blocks
  const int xcd = bid & 7;
  const int idx = bid >> 3;                  // 0..255
  const int e   = xcd * 8 + (idx >> 5);      // 8 experts per XCD
  const int rem = idx & 31;
  const int mb  = rem >> 3;
  const int nb  = rem & 7;
  const int b0 = mb * 128;
  const int o0 = nb * 128;
  const int tid  = threadIdx.x;
  const int wave = tid >> 6;
  const int lane = tid & 63;
  const int l15 = lane & 15, l4 = lane >> 4;
  const int wm = (wave & 1) * 64;
  const int wn = (wave >> 1) * 64;

  __shared__ __attribute__((aligned(16))) uint32_t Al[128 * 32]; // [m][64 bf16] swizzled
  __shared__ __attribute__((aligned(16))) uint32_t Wl[128 * 32]; // [o][64 bf16] swizzled

  f32x4 acc[4][4];
  #pragma unroll
  for (int i = 0; i < 4; ++i)
    #pragma unroll
    for (int j = 0; j < 4; ++j) acc[i][j] = (f32x4){0.f, 0.f, 0.f, 0.f};

  for (int ks = 0; ks < 4; ++ks) {
    // stage A (already bf16): 128 rows x 64k
    #pragma unroll
    for (int i = 0; i < 4; ++i) {
      int gi = tid + i * 256;
      int m = gi >> 3, q = gi & 7;
      const uint4v* src = (const uint4v*)(inp + ((size_t)(b0 + m) * Ee + e) * 256 + ks * 64 + q * 8);
      *(uint4v*)&Al[m * 32 + ((q ^ (m & 7)) * 4)] = *src;
    }
    // stage W with f32 -> bf16 conversion
    #pragma unroll
    for (int i = 0; i < 4; ++i) {
      int gi = tid + i * 256;
      int o = gi >> 3, q = gi & 7;
      const float* src = expert_w + ((size_t)e * OUTn + o0 + o) * 256 + ks * 64 + q * 8;
      f32x4 w0 = *(const f32x4*)src;
      f32x4 w1 = *(const f32x4*)(src + 4);
      uint4v v;
      v[0] = f2bf(w0[0]) | (f2bf(w0[1]) << 16);
      v[1] = f2bf(w0[2]) | (f2bf(w0[3]) << 16);
      v[2] = f2bf(w1[0]) | (f2bf(w1[1]) << 16);
      v[3] = f2bf(w1[2]) | (f2bf(w1[3]) << 16);
      *(uint4v*)&Wl[o * 32 + ((q ^ (o & 7)) * 4)] = v;
    }
    __syncthreads();

    short8 af[4][2], bf[4][2];
    #pragma unroll
    for (int mf = 0; mf < 4; ++mf)
      #pragma unroll
      for (int kb = 0; kb < 2; ++kb) {
        int row = wm + mf * 16 + l15;
        int g = kb * 4 + l4;
        af[mf][kb] = *(const short8*)&Al[row * 32 + ((g ^ (row & 7)) * 4)];
      }
    #pragma unroll
    for (int nf = 0; nf < 4; ++nf)
      #pragma unroll
      for (int kb = 0; kb < 2; ++kb) {
        int row = wn + nf * 16 + l15;
        int g = kb * 4 + l4;
        bf[nf][kb] = *(const short8*)&Wl[row * 32 + ((g ^ (row & 7)) * 4)];
      }
    #pragma unroll
    for (int mf = 0; mf < 4; ++mf)
      #pragma unroll
      for (int nf = 0; nf < 4; ++nf)
        #pragma unroll
        for (int kb = 0; kb < 2; ++kb)
          acc[mf][nf] = __builtin_amdgcn_mfma_f32_16x16x32_bf16(af[mf][kb], bf[nf][kb], acc[mf][nf], 0, 0, 0);
    __syncthreads();
  }

  // epilogue: D col = lane&15 -> o, row = (lane>>4)*4+reg -> b-row
  #pragma unroll
  for (int nf = 0; nf < 4; ++nf) {
    const int ocol = o0 + wn + nf * 16 + l15;
    const float bias = expert_b[(size_t)e * OUTn + ocol];
    #pragma unroll
    for (int mf = 0; mf < 4; ++mf) {
      #pragma unroll
      for (int reg = 0; reg < 4; ++reg) {
        const int mrow = b0 + wm + mf * 16 + l4 * 4 + reg;
        out[((size_t)mrow * Ee + e) * OUTn + ocol] = acc[mf][nf][reg] + bias;
      }
    }
  }
}

extern "C" void kernel_launch(void* const* d_in, const int* in_sizes, int n_in,
                              void* d_out, int out_size, void* d_ws, size_t ws_size,
                              hipStream_t stream) {
  const float* x        = (const float*)d_in[0];
  const float* gate_w   = (const float*)d_in[1];
  // d_in[2] = gate_b: constant per expert -> cannot change per-(b,e) top-k
  // ordering over tokens (and is zeros); values are never used downstream.
  const float* expert_w = (const float*)d_in[3];
  const float* expert_b = (const float*)d_in[4];
  const float* gumbel   = (const float*)d_in[5];

  uint16_t* inp = (uint16_t*)d_ws;   // 512*64*256*2 = 16.8 MB

  kA_select<<<Bb, 512, 0, stream>>>(x, gate_w, gumbel, inp);
  kB_gemm<<<2048, 256, 0, stream>>>(inp, expert_w, expert_b, (float*)d_out);
}